// Round 1
// 1362.229 us; speedup vs baseline: 1.2464x; 1.2464x over previous
//
#include <hip/hip_runtime.h>
#include <hip/hip_bf16.h>

#define B_SZ   4096
#define NPC    32
#define NJ     100
#define CD     16
#define PD     8

typedef float  f32x4  __attribute__((ext_vector_type(4)));
typedef __bf16 bf16x8 __attribute__((ext_vector_type(8)));

__device__ __forceinline__ unsigned short f2bfr(float f) {
    union { float f; unsigned u; } v; v.f = f;
    return (unsigned short)((v.u + 0x8000u) >> 16);   // round-half-up to bf16
}
__device__ __forceinline__ float bf_lo(unsigned u) {
    union { unsigned u; float f; } v; v.u = u << 16; return v.f;
}
__device__ __forceinline__ float bf_hi(unsigned u) {
    union { unsigned u; float f; } v; v.u = u & 0xffff0000u; return v.f;
}

// ---------------------------------------------------------------------------
// W1 [20000][512] fp32  ->  Bt [512][20000] bf16 (transpose + convert)
// ---------------------------------------------------------------------------
__global__ __launch_bounds__(256) void transpose_cvt(
    const float* __restrict__ W, unsigned short* __restrict__ out)
{
    __shared__ float tile[32][33];
    const int kb = blockIdx.x * 32;     // 625 blocks
    const int nb = blockIdx.y * 32;     // 16 blocks
    const int tx = threadIdx.x & 31, ty = threadIdx.x >> 5;
#pragma unroll
    for (int i = 0; i < 4; ++i)
        tile[ty + 8 * i][tx] = W[(size_t)(kb + ty + 8 * i) * 512 + nb + tx];
    __syncthreads();
#pragma unroll
    for (int i = 0; i < 4; ++i)
        out[(size_t)(nb + ty + 8 * i) * 20000 + kb + tx] = f2bfr(tile[tx][ty + 8 * i]);
}

// ---------------------------------------------------------------------------
// GEMM1 (MFMA bf16): C += features @ W1.  128x128 tile, BK=32, split-K=5.
// A (fp32) converted to bf16 during staging; Bt is pre-converted bf16 [N][K].
// Grid swizzle: id = z*128 + n*32 + m  -> n-quads of one m-slice share an XCD.
// ---------------------------------------------------------------------------
__global__ __launch_bounds__(256) void gemm1_mfma(
    const float* __restrict__ A,            // [4096][20000] fp32
    const unsigned short* __restrict__ Bt,  // [512][20000] bf16
    float* __restrict__ C)                  // [4096][512] fp32 (zeroed)
{
    __shared__ __align__(16) unsigned short As[128 * 32];
    __shared__ __align__(16) unsigned short Bs[128 * 32];
    const int t = threadIdx.x;
    const int lane = t & 63, w = t >> 6;
    const int id = blockIdx.x;
    const int m0 = (id & 31) * 128;
    const int n0 = ((id >> 5) & 3) * 128;
    const int z  = id >> 7;                 // 0..4, K chunk of 4000

    const int srow = t >> 2, skc = t & 3;   // staging: slot t -> row, k-chunk
    const float*          Ap  = A  + (size_t)(m0 + srow) * 20000 + z * 4000 + skc * 8;
    const float*          Ap2 = Ap + (size_t)64 * 20000;
    const unsigned short* Bp  = Bt + (size_t)(n0 + srow) * 20000 + z * 4000 + skc * 8;
    const unsigned short* Bp2 = Bp + (size_t)64 * 20000;

    const int wr = w >> 1, wc = w & 1;      // wave -> 64x64 quadrant
    const int fr = lane & 15, fq = lane >> 4;

    f32x4 acc[4][4] = {};

    for (int kt = 0; kt < 125; ++kt) {
        const int k0 = kt * 32;
        float4 a0 = *(const float4*)(Ap  + k0);
        float4 a1 = *(const float4*)(Ap  + k0 + 4);
        float4 a2 = *(const float4*)(Ap2 + k0);
        float4 a3 = *(const float4*)(Ap2 + k0 + 4);
        uint4  q0 = *(const uint4*)(Bp  + k0);
        uint4  q1 = *(const uint4*)(Bp2 + k0);
        uint4 p0, p1;
        p0.x = (unsigned)f2bfr(a0.x) | ((unsigned)f2bfr(a0.y) << 16);
        p0.y = (unsigned)f2bfr(a0.z) | ((unsigned)f2bfr(a0.w) << 16);
        p0.z = (unsigned)f2bfr(a1.x) | ((unsigned)f2bfr(a1.y) << 16);
        p0.w = (unsigned)f2bfr(a1.z) | ((unsigned)f2bfr(a1.w) << 16);
        p1.x = (unsigned)f2bfr(a2.x) | ((unsigned)f2bfr(a2.y) << 16);
        p1.y = (unsigned)f2bfr(a2.z) | ((unsigned)f2bfr(a2.w) << 16);
        p1.z = (unsigned)f2bfr(a3.x) | ((unsigned)f2bfr(a3.y) << 16);
        p1.w = (unsigned)f2bfr(a3.z) | ((unsigned)f2bfr(a3.w) << 16);
        *(uint4*)(As + (size_t)t * 8)         = p0;
        *(uint4*)(As + (size_t)(t + 256) * 8) = p1;
        *(uint4*)(Bs + (size_t)t * 8)         = q0;
        *(uint4*)(Bs + (size_t)(t + 256) * 8) = q1;
        __syncthreads();
        bf16x8 af[4], bg[4];
#pragma unroll
        for (int mi = 0; mi < 4; ++mi)
            af[mi] = *(const bf16x8*)(As + (size_t)((wr * 64 + mi * 16 + fr) * 32 + fq * 8));
#pragma unroll
        for (int ni = 0; ni < 4; ++ni)
            bg[ni] = *(const bf16x8*)(Bs + (size_t)((wc * 64 + ni * 16 + fr) * 32 + fq * 8));
#pragma unroll
        for (int mi = 0; mi < 4; ++mi)
#pragma unroll
            for (int ni = 0; ni < 4; ++ni)
                acc[mi][ni] = __builtin_amdgcn_mfma_f32_16x16x32_bf16(
                    af[mi], bg[ni], acc[mi][ni], 0, 0, 0);
        __syncthreads();
    }

    // epilogue: C/D layout col=lane&15, row=(lane>>4)*4+reg
    const int er = fq * 4, ec = fr;
#pragma unroll
    for (int mi = 0; mi < 4; ++mi)
#pragma unroll
    for (int ni = 0; ni < 4; ++ni) {
        const size_t base = (size_t)(m0 + wr * 64 + mi * 16 + er) * 512
                          + n0 + wc * 64 + ni * 16 + ec;
#pragma unroll
        for (int r = 0; r < 4; ++r)
            atomicAdd(&C[base + (size_t)r * 512], acc[mi][ni][r]);
    }
}

// ---------------------------------------------------------------------------
// GEMM2: C = relu( relu(A + b1) @ B + b2 ), 64x64 tile (A = raw gemm1 sums)
// ---------------------------------------------------------------------------
__global__ __launch_bounds__(256) void gemm2_fused(
    const float* __restrict__ A, const float* __restrict__ b1v,
    const float* __restrict__ Bm, const float* __restrict__ bias,
    float* __restrict__ C, int M, int N, int K)
{
    __shared__ float As[16][68];
    __shared__ float Bs[16][64];
    const int t  = threadIdx.x;
    const int tx = t & 15, ty = t >> 4;
    const int m0 = blockIdx.y * 64, n0 = blockIdx.x * 64;

    const int arow = t >> 2;
    const int ak   = (t & 3) << 2;
    const int bk   = t >> 4;
    const int bn   = (t & 15) << 2;

    const float* Aptr = A + (size_t)(m0 + arow) * K + ak;
    const float* Bptr = Bm + (size_t)bk * N + n0 + bn;

    float acc[4][4] = {};

    for (int k0 = 0; k0 < K; k0 += 16) {
        float4 av  = *(const float4*)(Aptr + k0);
        float4 b1q = *(const float4*)(b1v + k0 + ak);
        av.x = fmaxf(av.x + b1q.x, 0.f);
        av.y = fmaxf(av.y + b1q.y, 0.f);
        av.z = fmaxf(av.z + b1q.z, 0.f);
        av.w = fmaxf(av.w + b1q.w, 0.f);
        float4 bv = *(const float4*)(Bptr + (size_t)k0 * N);
        As[ak + 0][arow] = av.x;
        As[ak + 1][arow] = av.y;
        As[ak + 2][arow] = av.z;
        As[ak + 3][arow] = av.w;
        *(float4*)&Bs[bk][bn] = bv;
        __syncthreads();
#pragma unroll
        for (int kk = 0; kk < 16; ++kk) {
            float4 a = *(const float4*)&As[kk][ty << 2];
            float4 b = *(const float4*)&Bs[kk][tx << 2];
            acc[0][0] += a.x * b.x; acc[0][1] += a.x * b.y; acc[0][2] += a.x * b.z; acc[0][3] += a.x * b.w;
            acc[1][0] += a.y * b.x; acc[1][1] += a.y * b.y; acc[1][2] += a.y * b.z; acc[1][3] += a.y * b.w;
            acc[2][0] += a.z * b.x; acc[2][1] += a.z * b.y; acc[2][2] += a.z * b.z; acc[2][3] += a.z * b.w;
            acc[3][0] += a.w * b.x; acc[3][1] += a.w * b.y; acc[3][2] += a.w * b.z; acc[3][3] += a.w * b.w;
        }
        __syncthreads();
    }

    float4 bb = *(const float4*)(bias + n0 + (tx << 2));
#pragma unroll
    for (int i = 0; i < 4; ++i) {
        size_t m = (size_t)m0 + (ty << 2) + i;
        float4 o;
        o.x = fmaxf(acc[i][0] + bb.x, 0.f);
        o.y = fmaxf(acc[i][1] + bb.y, 0.f);
        o.z = fmaxf(acc[i][2] + bb.z, 0.f);
        o.w = fmaxf(acc[i][3] + bb.w, 0.f);
        *(float4*)(C + m * N + n0 + (tx << 2)) = o;
    }
}

// ---------------------------------------------------------------------------
// LayerNorm over 256 features, 1 wave per row, 4 rows per block
// ---------------------------------------------------------------------------
__global__ __launch_bounds__(256) void layernorm256(
    const float* __restrict__ x, const float* __restrict__ g,
    const float* __restrict__ bta, float* __restrict__ y)
{
    const int w = threadIdx.x >> 6, lane = threadIdx.x & 63;
    const size_t row = (size_t)blockIdx.x * 4 + w;
    const float* xr = x + row * 256;
    float4 v = *(const float4*)(xr + lane * 4);
    float s  = v.x + v.y + v.z + v.w;
    float s2 = v.x * v.x + v.y * v.y + v.z * v.z + v.w * v.w;
#pragma unroll
    for (int off = 32; off; off >>= 1) {
        s  += __shfl_down(s, off);
        s2 += __shfl_down(s2, off);
    }
    s  = __shfl(s, 0);
    s2 = __shfl(s2, 0);
    float mu   = s * (1.f / 256.f);
    float var  = s2 * (1.f / 256.f) - mu * mu;
    float rstd = rsqrtf(var + 1e-5f);
    float4 gg = *(const float4*)(g + lane * 4);
    float4 bb = *(const float4*)(bta + lane * 4);
    float4 o;
    o.x = (v.x - mu) * rstd * gg.x + bb.x;
    o.y = (v.y - mu) * rstd * gg.y + bb.y;
    o.z = (v.z - mu) * rstd * gg.z + bb.z;
    o.w = (v.w - mu) * rstd * gg.w + bb.w;
    *(float4*)(y + row * 256 + lane * 4) = o;
}

// ---------------------------------------------------------------------------
// Primary caps: prim[b,n,d] = LN_d( h[b,:] @ pc_W[n,:,d] + pc_b[n,d] ) * g + beta
// ---------------------------------------------------------------------------
__global__ __launch_bounds__(256) void prim_caps(
    const float* __restrict__ h, const float* __restrict__ pcW,
    const float* __restrict__ pcB, const float* __restrict__ pcG,
    const float* __restrict__ pcBeta, float* __restrict__ prim)
{
    __shared__ float hs[256];
    __shared__ float tmp[256];
    const int t = threadIdx.x;
    const size_t b = blockIdx.x;
    hs[t] = h[b * 256 + t];
    __syncthreads();
    const int n = t >> 3, d = t & 7;
    const float* wp = pcW + n * 256 * 8 + d;
    float acc = pcB[t];
#pragma unroll 4
    for (int k = 0; k < 256; ++k) acc += hs[k] * wp[k * 8];
    tmp[t] = acc;
    __syncthreads();
    float mu = 0.f, s2 = 0.f;
    const int base = n << 3;
#pragma unroll
    for (int q = 0; q < 8; ++q) {
        float xx = tmp[base + q];
        mu += xx;
        s2 += xx * xx;
    }
    mu *= 0.125f;
    s2 = s2 * 0.125f - mu * mu;
    float rstd = rsqrtf(s2 + 1e-5f);
    prim[b * 256 + t] = (acc - mu) * rstd * pcG[t] + pcBeta[t];
}

// ---------------------------------------------------------------------------
// Routing, 1 batch row per block, 1024 threads (16 waves -> 4 waves/SIMD).
// LDS is ~150 KiB so only 1 block/CU fits; the extra waves are the only way
// to raise occupancy past 25%. pred materialized ONCE in LDS (bf16 pairs,
// stride 9 words -> conflict-free); b-state fp32 in LDS.
// ---------------------------------------------------------------------------
__global__ __launch_bounds__(1024, 4) void routing_b1(
    const float* __restrict__ prim,     // [B,32,8]
    const float* __restrict__ sf,       // [B,100]
    const float* __restrict__ priors,   // [100,100]
    const float* __restrict__ dcW,      // [32,100,16,8]
    const float* __restrict__ targets,  // [100,16]
    const float* __restrict__ temp_p,
    float* __restrict__ out)            // [B,100]
{
    __shared__ float    prim1[256];
    __shared__ unsigned predp[NPC * NJ * 9];   // [n*100+j][op0..7], stride 9: 115200 B
    __shared__ float    bst[NPC * NJ];         // fp32 b-state
    __shared__ float    cst[NPC * NJ];         // softmax coupling c
    __shared__ float    svv[NJ * 18];          // v vectors, stride 18
    __shared__ float    spv[NJ];
    __shared__ float    rmv[NPC], irsv[NPC];
    __shared__ float    red[512];
    __shared__ float    red2[400];
    __shared__ float    ssum;

    const int t = threadIdx.x;                 // 0..1023
    const int lane = t & 63, w = t >> 6;       // w 0..15

    const size_t b = blockIdx.x;

    if (t < 256) prim1[t] = prim[b * 256 + t];
    if (t < 128) red[t] = (t < 100) ? fmaxf(sf[b * 100 + t], 0.f) : 0.f;
    __syncthreads();

    // sum of relu (2 waves reduce)
    if (t < 128) {
        float v = red[t];
#pragma unroll
        for (int d = 32; d; d >>= 1) v += __shfl_xor(v, d);
        if (lane == 0) red[128 + w] = v;
    }
    __syncthreads();
    if (t == 0) ssum = fmaxf(red[128] + red[129], 1e-6f);
    __syncthreads();

    // sp[j] = sum_k (relu_k/ssum - 0.01) * priors[k][j]   (4-way k-split)
    if (t < 400) {
        const int j = t % 100, q = t / 100;
        const float inv = 1.f / ssum;
        float acc = 0.f;
#pragma unroll 5
        for (int k = q * 25; k < q * 25 + 25; ++k)
            acc += (red[k] * inv - 0.01f) * priors[k * 100 + j];
        red2[t] = acc;
    }
    __syncthreads();
    if (t < 100) spv[t] = red2[t] + red2[100 + t] + red2[200 + t] + red2[300 + t];
    __syncthreads();

    // b init
    for (int r = t; r < NPC * NJ; r += 1024) bst[r] = spv[r % 100] * 0.1f;

    // ---- pred phase: half-wave (32 lanes) per (n,j) pair; 32 pairs/iter ----
    {
        const int c32 = lane & 31;
        const int hw  = t >> 5;                // half-wave id 0..31
        const int ih  = (c32 & 1) * 4;
#pragma unroll 4
        for (int iter = 0; iter < 100; ++iter) {
            const int p = iter * 32 + hw;      // (n,j) pair 0..3199
            const int n = p / 100;
            const float4 wv = *(const float4*)(dcW + (size_t)p * 128 + c32 * 4);
            const float* pb = &prim1[n * 8 + ih];
            float part = wv.x * pb[0] + wv.y * pb[1] + wv.z * pb[2] + wv.w * pb[3];
            float po  = part + __shfl_xor(part, 1);        // pred[o], o=c32>>1
            float po2 = __shfl_xor(po, 2);                 // pred[o+1]
            if ((c32 & 3) == 0)
                predp[p * 9 + (c32 >> 2)] =
                    (unsigned)f2bfr(po) | ((unsigned)f2bfr(po2) << 16);
        }
    }
    __syncthreads();

    // ---- routing iterations ----
    for (int it = 0; it < 3; ++it) {
        // softmax stats per (n): 32 n x 32 lanes
        {
            const int n = t >> 5, q = t & 31;
            float mx = -1e30f;
            for (int j = q; j < 100; j += 32) mx = fmaxf(mx, bst[n * 100 + j]);
#pragma unroll
            for (int d = 1; d < 32; d <<= 1) mx = fmaxf(mx, __shfl_xor(mx, d));
            float se = 0.f;
            for (int j = q; j < 100; j += 32) se += __expf(bst[n * 100 + j] - mx);
#pragma unroll
            for (int d = 1; d < 32; d <<= 1) se += __shfl_xor(se, d);
            if (q == 0) { rmv[n] = mx; irsv[n] = 1.f / se; }
        }
        __syncthreads();
        for (int r = t; r < NPC * NJ; r += 1024)
            cst[r] = __expf(bst[r] - rmv[r / 100]) * irsv[r / 100];
        __syncthreads();

        // s-pass + squash: item = (j, op), 800 items, 1 per thread
        if (t < 800) {
            const int j = t >> 3, op = t & 7;
            float s0 = 0.f, s1 = 0.f;
#pragma unroll
            for (int n = 0; n < NPC; ++n) {
                const float c = cst[n * 100 + j];
                const unsigned pk = predp[(n * 100 + j) * 9 + op];
                s0 += c * bf_lo(pk);
                s1 += c * bf_hi(pk);
            }
            float sq = s0 * s0 + s1 * s1;
            sq += __shfl_xor(sq, 1);
            sq += __shfl_xor(sq, 2);
            sq += __shfl_xor(sq, 4);
            const float fv = (sq / (1.f + sq)) / sqrtf(sq + 1e-8f);
            svv[j * 18 + op * 2]     = fv * s0;
            svv[j * 18 + op * 2 + 1] = fv * s1;
        }
        __syncthreads();

        // a-pass: b += pred.v + sp*strength
        if (it < 2) {
            const float str = 0.1f - 0.02f * (float)(it + 1);
            for (int r = t; r < NPC * NJ; r += 1024) {
                const int j = r % 100;
                float a = 0.f;
#pragma unroll
                for (int op = 0; op < 8; ++op) {
                    const unsigned pk = predp[r * 9 + op];
                    const float2 vv = *(const float2*)&svv[j * 18 + op * 2];
                    a += bf_lo(pk) * vv.x + bf_hi(pk) * vv.y;
                }
                bst[r] += a + spv[j] * str;
            }
            __syncthreads();
        }
    }

    // ---- final: l2norm + logits ----
    if (t < 100) {
        const float T = *temp_p;
        float sq = 0.f, lg = 0.f;
#pragma unroll
        for (int o = 0; o < CD; ++o) {
            const float v = svv[t * 18 + o];
            sq += v * v;
            lg += v * targets[t * CD + o];
        }
        out[b * 100 + t] = lg * T / fmaxf(sqrtf(sq), 1e-12f);
    }
}

// ---------------------------------------------------------------------------
extern "C" void kernel_launch(void* const* d_in, const int* in_sizes, int n_in,
                              void* d_out, int out_size, void* d_ws, size_t ws_size,
                              hipStream_t stream)
{
    const float* features      = (const float*)d_in[0];
    const float* slot_features = (const float*)d_in[1];
    const float* W1            = (const float*)d_in[2];
    const float* b1            = (const float*)d_in[3];
    const float* W2            = (const float*)d_in[4];
    const float* b2            = (const float*)d_in[5];
    const float* ln_g          = (const float*)d_in[6];
    const float* ln_b          = (const float*)d_in[7];
    const float* pc_W          = (const float*)d_in[8];
    const float* pc_b          = (const float*)d_in[9];
    const float* pc_g          = (const float*)d_in[10];
    const float* pc_beta       = (const float*)d_in[11];
    const float* dc_W          = (const float*)d_in[12];
    const float* slot_priors   = (const float*)d_in[13];
    const float* targets       = (const float*)d_in[14];
    const float* temperature   = (const float*)d_in[15];
    float* out = (float*)d_out;

    unsigned short* Bt = (unsigned short*)d_ws;                    // 512*20000 bf16 = 20.48 MB
    float* h1 = (float*)((char*)d_ws + (size_t)512 * 20000 * 2);   // 4096*512
    float* h2 = h1 + (size_t)B_SZ * 512;                           // 4096*256
    float* h  = h2 + (size_t)B_SZ * 256;
    float* pr = h  + (size_t)B_SZ * 256;

    hipMemsetAsync(h1, 0, (size_t)B_SZ * 512 * sizeof(float), stream);

    transpose_cvt<<<dim3(625, 16), 256, 0, stream>>>(W1, Bt);
    gemm1_mfma<<<640, 256, 0, stream>>>(features, Bt, h1);
    gemm2_fused<<<dim3(256 / 64, B_SZ / 64), 256, 0, stream>>>(
        h1, b1, W2, b2, h2, B_SZ, 256, 512);
    layernorm256<<<B_SZ / 4, 256, 0, stream>>>(h2, ln_g, ln_b, h);
    prim_caps<<<B_SZ, 256, 0, stream>>>(h, pc_W, pc_b, pc_g, pc_beta, pr);
    routing_b1<<<B_SZ, 1024, 0, stream>>>(
        pr, slot_features, slot_priors, dc_W, targets, temperature, out);
}

// Round 2
// 1211.649 us; speedup vs baseline: 1.4013x; 1.1243x over previous
//
#include <hip/hip_runtime.h>
#include <hip/hip_bf16.h>

#define B_SZ   4096
#define NPC    32
#define NJ     100
#define CD     16
#define PD     8

typedef float  f32x4  __attribute__((ext_vector_type(4)));
typedef __bf16 bf16x8 __attribute__((ext_vector_type(8)));

__device__ __forceinline__ unsigned short f2bfr(float f) {
    union { float f; unsigned u; } v; v.f = f;
    return (unsigned short)((v.u + 0x8000u) >> 16);   // round-half-up to bf16
}
__device__ __forceinline__ float bf_lo(unsigned u) {
    union { unsigned u; float f; } v; v.u = u << 16; return v.f;
}
__device__ __forceinline__ float bf_hi(unsigned u) {
    union { unsigned u; float f; } v; v.u = u & 0xffff0000u; return v.f;
}

// ---------------------------------------------------------------------------
// W1 [20000][512] fp32  ->  Bt [512][20000] bf16 (transpose + convert)
// ---------------------------------------------------------------------------
__global__ __launch_bounds__(256) void transpose_cvt(
    const float* __restrict__ W, unsigned short* __restrict__ out)
{
    __shared__ float tile[32][33];
    const int kb = blockIdx.x * 32;     // 625 blocks
    const int nb = blockIdx.y * 32;     // 16 blocks
    const int tx = threadIdx.x & 31, ty = threadIdx.x >> 5;
#pragma unroll
    for (int i = 0; i < 4; ++i)
        tile[ty + 8 * i][tx] = W[(size_t)(kb + ty + 8 * i) * 512 + nb + tx];
    __syncthreads();
#pragma unroll
    for (int i = 0; i < 4; ++i)
        out[(size_t)(nb + ty + 8 * i) * 20000 + kb + tx] = f2bfr(tile[tx][ty + 8 * i]);
}

// ---------------------------------------------------------------------------
// dc_W [32*100*16*8] fp32 -> bf16, same element order
// ---------------------------------------------------------------------------
__global__ __launch_bounds__(256) void cvt_dcw(
    const float* __restrict__ W, unsigned short* __restrict__ out)
{
    const size_t i = ((size_t)blockIdx.x * 256 + threadIdx.x) * 8;  // 409600 total
    float4 f0 = *(const float4*)(W + i);
    float4 f1 = *(const float4*)(W + i + 4);
    uint4 o;
    o.x = (unsigned)f2bfr(f0.x) | ((unsigned)f2bfr(f0.y) << 16);
    o.y = (unsigned)f2bfr(f0.z) | ((unsigned)f2bfr(f0.w) << 16);
    o.z = (unsigned)f2bfr(f1.x) | ((unsigned)f2bfr(f1.y) << 16);
    o.w = (unsigned)f2bfr(f1.z) | ((unsigned)f2bfr(f1.w) << 16);
    *(uint4*)(out + i) = o;
}

// ---------------------------------------------------------------------------
// GEMM1 (MFMA bf16): C += features @ W1.  64x256 tile, BK=32, split-K=5.
// BN=256 halves A re-reads (1.31 GB -> 0.66 GB HBM); B tile (2 MB per (n,z)
// slice) stays L2-resident per XCD. Per-wave 64x64 quadrant, acc[4][4] --
// identical MFMA/epilogue structure to the verified 128x128 version.
// ---------------------------------------------------------------------------
__global__ __launch_bounds__(256) void gemm1_mfma(
    const float* __restrict__ A,            // [4096][20000] fp32
    const unsigned short* __restrict__ Bt,  // [512][20000] bf16
    float* __restrict__ C)                  // [4096][512] fp32 (zeroed)
{
    __shared__ __align__(16) unsigned short As[64 * 32];    // 4 KB
    __shared__ __align__(16) unsigned short Bs[256 * 32];   // 16 KB
    const int t = threadIdx.x;
    const int lane = t & 63, w = t >> 6;
    const int id = blockIdx.x;
    const int m0 = (id & 63) * 64;          // 64 m-blocks
    const int n0 = ((id >> 6) & 1) * 256;   // 2 n-blocks
    const int z  = id >> 7;                 // 0..4, K chunk of 4000

    const int srow = t >> 2, skc = t & 3;   // staging: row 0..63, k-chunk 0..3
    const float*          Ap  = A  + (size_t)(m0 + srow) * 20000 + z * 4000 + skc * 8;
    const unsigned short* Bp  = Bt + (size_t)(n0 + srow) * 20000 + z * 4000 + skc * 8;

    const int fr = lane & 15, fq = lane >> 4;

    f32x4 acc[4][4] = {};

    for (int kt = 0; kt < 125; ++kt) {
        const int k0 = kt * 32;
        float4 a0 = *(const float4*)(Ap + k0);
        float4 a1 = *(const float4*)(Ap + k0 + 4);
        uint4  q0 = *(const uint4*)(Bp + k0);
        uint4  q1 = *(const uint4*)(Bp + (size_t)64  * 20000 + k0);
        uint4  q2 = *(const uint4*)(Bp + (size_t)128 * 20000 + k0);
        uint4  q3 = *(const uint4*)(Bp + (size_t)192 * 20000 + k0);
        uint4 p0;
        p0.x = (unsigned)f2bfr(a0.x) | ((unsigned)f2bfr(a0.y) << 16);
        p0.y = (unsigned)f2bfr(a0.z) | ((unsigned)f2bfr(a0.w) << 16);
        p0.z = (unsigned)f2bfr(a1.x) | ((unsigned)f2bfr(a1.y) << 16);
        p0.w = (unsigned)f2bfr(a1.z) | ((unsigned)f2bfr(a1.w) << 16);
        *(uint4*)(As + (size_t)t * 8)         = p0;
        *(uint4*)(Bs + (size_t)t * 8)         = q0;
        *(uint4*)(Bs + (size_t)(t + 256) * 8) = q1;
        *(uint4*)(Bs + (size_t)(t + 512) * 8) = q2;
        *(uint4*)(Bs + (size_t)(t + 768) * 8) = q3;
        __syncthreads();
        bf16x8 af[4], bg[4];
#pragma unroll
        for (int mi = 0; mi < 4; ++mi)
            af[mi] = *(const bf16x8*)(As + (size_t)((mi * 16 + fr) * 32 + fq * 8));
#pragma unroll
        for (int ni = 0; ni < 4; ++ni)
            bg[ni] = *(const bf16x8*)(Bs + (size_t)((w * 64 + ni * 16 + fr) * 32 + fq * 8));
#pragma unroll
        for (int mi = 0; mi < 4; ++mi)
#pragma unroll
            for (int ni = 0; ni < 4; ++ni)
                acc[mi][ni] = __builtin_amdgcn_mfma_f32_16x16x32_bf16(
                    af[mi], bg[ni], acc[mi][ni], 0, 0, 0);
        __syncthreads();
    }

    // epilogue: C/D layout col=lane&15, row=(lane>>4)*4+reg
    const int er = fq * 4, ec = fr;
#pragma unroll
    for (int mi = 0; mi < 4; ++mi)
#pragma unroll
    for (int ni = 0; ni < 4; ++ni) {
        const size_t base = (size_t)(m0 + mi * 16 + er) * 512
                          + n0 + w * 64 + ni * 16 + ec;
#pragma unroll
        for (int r = 0; r < 4; ++r)
            atomicAdd(&C[base + (size_t)r * 512], acc[mi][ni][r]);
    }
}

// ---------------------------------------------------------------------------
// GEMM2: C = relu( relu(A + b1) @ B + b2 ), 64x64 tile (A = raw gemm1 sums)
// ---------------------------------------------------------------------------
__global__ __launch_bounds__(256) void gemm2_fused(
    const float* __restrict__ A, const float* __restrict__ b1v,
    const float* __restrict__ Bm, const float* __restrict__ bias,
    float* __restrict__ C, int M, int N, int K)
{
    __shared__ float As[16][68];
    __shared__ float Bs[16][64];
    const int t  = threadIdx.x;
    const int tx = t & 15, ty = t >> 4;
    const int m0 = blockIdx.y * 64, n0 = blockIdx.x * 64;

    const int arow = t >> 2;
    const int ak   = (t & 3) << 2;
    const int bk   = t >> 4;
    const int bn   = (t & 15) << 2;

    const float* Aptr = A + (size_t)(m0 + arow) * K + ak;
    const float* Bptr = Bm + (size_t)bk * N + n0 + bn;

    float acc[4][4] = {};

    for (int k0 = 0; k0 < K; k0 += 16) {
        float4 av  = *(const float4*)(Aptr + k0);
        float4 b1q = *(const float4*)(b1v + k0 + ak);
        av.x = fmaxf(av.x + b1q.x, 0.f);
        av.y = fmaxf(av.y + b1q.y, 0.f);
        av.z = fmaxf(av.z + b1q.z, 0.f);
        av.w = fmaxf(av.w + b1q.w, 0.f);
        float4 bv = *(const float4*)(Bptr + (size_t)k0 * N);
        As[ak + 0][arow] = av.x;
        As[ak + 1][arow] = av.y;
        As[ak + 2][arow] = av.z;
        As[ak + 3][arow] = av.w;
        *(float4*)&Bs[bk][bn] = bv;
        __syncthreads();
#pragma unroll
        for (int kk = 0; kk < 16; ++kk) {
            float4 a = *(const float4*)&As[kk][ty << 2];
            float4 b = *(const float4*)&Bs[kk][tx << 2];
            acc[0][0] += a.x * b.x; acc[0][1] += a.x * b.y; acc[0][2] += a.x * b.z; acc[0][3] += a.x * b.w;
            acc[1][0] += a.y * b.x; acc[1][1] += a.y * b.y; acc[1][2] += a.y * b.z; acc[1][3] += a.y * b.w;
            acc[2][0] += a.z * b.x; acc[2][1] += a.z * b.y; acc[2][2] += a.z * b.z; acc[2][3] += a.z * b.w;
            acc[3][0] += a.w * b.x; acc[3][1] += a.w * b.y; acc[3][2] += a.w * b.z; acc[3][3] += a.w * b.w;
        }
        __syncthreads();
    }

    float4 bb = *(const float4*)(bias + n0 + (tx << 2));
#pragma unroll
    for (int i = 0; i < 4; ++i) {
        size_t m = (size_t)m0 + (ty << 2) + i;
        float4 o;
        o.x = fmaxf(acc[i][0] + bb.x, 0.f);
        o.y = fmaxf(acc[i][1] + bb.y, 0.f);
        o.z = fmaxf(acc[i][2] + bb.z, 0.f);
        o.w = fmaxf(acc[i][3] + bb.w, 0.f);
        *(float4*)(C + m * N + n0 + (tx << 2)) = o;
    }
}

// ---------------------------------------------------------------------------
// LayerNorm over 256 features, 1 wave per row, 4 rows per block
// ---------------------------------------------------------------------------
__global__ __launch_bounds__(256) void layernorm256(
    const float* __restrict__ x, const float* __restrict__ g,
    const float* __restrict__ bta, float* __restrict__ y)
{
    const int w = threadIdx.x >> 6, lane = threadIdx.x & 63;
    const size_t row = (size_t)blockIdx.x * 4 + w;
    const float* xr = x + row * 256;
    float4 v = *(const float4*)(xr + lane * 4);
    float s  = v.x + v.y + v.z + v.w;
    float s2 = v.x * v.x + v.y * v.y + v.z * v.z + v.w * v.w;
#pragma unroll
    for (int off = 32; off; off >>= 1) {
        s  += __shfl_down(s, off);
        s2 += __shfl_down(s2, off);
    }
    s  = __shfl(s, 0);
    s2 = __shfl(s2, 0);
    float mu   = s * (1.f / 256.f);
    float var  = s2 * (1.f / 256.f) - mu * mu;
    float rstd = rsqrtf(var + 1e-5f);
    float4 gg = *(const float4*)(g + lane * 4);
    float4 bb = *(const float4*)(bta + lane * 4);
    float4 o;
    o.x = (v.x - mu) * rstd * gg.x + bb.x;
    o.y = (v.y - mu) * rstd * gg.y + bb.y;
    o.z = (v.z - mu) * rstd * gg.z + bb.z;
    o.w = (v.w - mu) * rstd * gg.w + bb.w;
    *(float4*)(y + row * 256 + lane * 4) = o;
}

// ---------------------------------------------------------------------------
// Primary caps: prim[b,n,d] = LN_d( h[b,:] @ pc_W[n,:,d] + pc_b[n,d] ) * g + beta
// ---------------------------------------------------------------------------
__global__ __launch_bounds__(256) void prim_caps(
    const float* __restrict__ h, const float* __restrict__ pcW,
    const float* __restrict__ pcB, const float* __restrict__ pcG,
    const float* __restrict__ pcBeta, float* __restrict__ prim)
{
    __shared__ float hs[256];
    __shared__ float tmp[256];
    const int t = threadIdx.x;
    const size_t b = blockIdx.x;
    hs[t] = h[b * 256 + t];
    __syncthreads();
    const int n = t >> 3, d = t & 7;
    const float* wp = pcW + n * 256 * 8 + d;
    float acc = pcB[t];
#pragma unroll 4
    for (int k = 0; k < 256; ++k) acc += hs[k] * wp[k * 8];
    tmp[t] = acc;
    __syncthreads();
    float mu = 0.f, s2 = 0.f;
    const int base = n << 3;
#pragma unroll
    for (int q = 0; q < 8; ++q) {
        float xx = tmp[base + q];
        mu += xx;
        s2 += xx * xx;
    }
    mu *= 0.125f;
    s2 = s2 * 0.125f - mu * mu;
    float rstd = rsqrtf(s2 + 1e-5f);
    prim[b * 256 + t] = (acc - mu) * rstd * pcG[t] + pcBeta[t];
}

// ---------------------------------------------------------------------------
// Routing, 1 batch row per block, 1024 threads (16 waves -> 4 waves/SIMD).
// LDS is ~150 KiB so only 1 block/CU fits. pred phase reads PRE-CONVERTED
// bf16 dcW (halves L2 traffic: 6.7 GB -> 3.35 GB across the dispatch); one
// lane per output o -> 1x16B load per 8 FMA, 1 shuffle per 2 outputs.
// ---------------------------------------------------------------------------
__global__ __launch_bounds__(1024, 4) void routing_b1(
    const float* __restrict__ prim,            // [B,32,8]
    const float* __restrict__ sf,              // [B,100]
    const float* __restrict__ priors,          // [100,100]
    const unsigned short* __restrict__ dcWb,   // [32,100,16,8] bf16
    const float* __restrict__ targets,         // [100,16]
    const float* __restrict__ temp_p,
    float* __restrict__ out)                   // [B,100]
{
    __shared__ __align__(16) float prim1[256];
    __shared__ unsigned predp[NPC * NJ * 9];   // [n*100+j][op0..7], stride 9: 115200 B
    __shared__ float    bst[NPC * NJ];         // fp32 b-state
    __shared__ float    cst[NPC * NJ];         // softmax coupling c
    __shared__ float    svv[NJ * 18];          // v vectors, stride 18
    __shared__ float    spv[NJ];
    __shared__ float    rmv[NPC], irsv[NPC];
    __shared__ float    red[512];
    __shared__ float    red2[400];
    __shared__ float    ssum;

    const int t = threadIdx.x;                 // 0..1023
    const int lane = t & 63, w = t >> 6;       // w 0..15

    const size_t b = blockIdx.x;

    if (t < 256) prim1[t] = prim[b * 256 + t];
    if (t < 128) red[t] = (t < 100) ? fmaxf(sf[b * 100 + t], 0.f) : 0.f;
    __syncthreads();

    // sum of relu (2 waves reduce)
    if (t < 128) {
        float v = red[t];
#pragma unroll
        for (int d = 32; d; d >>= 1) v += __shfl_xor(v, d);
        if (lane == 0) red[128 + w] = v;
    }
    __syncthreads();
    if (t == 0) ssum = fmaxf(red[128] + red[129], 1e-6f);
    __syncthreads();

    // sp[j] = sum_k (relu_k/ssum - 0.01) * priors[k][j]   (4-way k-split)
    if (t < 400) {
        const int j = t % 100, q = t / 100;
        const float inv = 1.f / ssum;
        float acc = 0.f;
#pragma unroll 5
        for (int k = q * 25; k < q * 25 + 25; ++k)
            acc += (red[k] * inv - 0.01f) * priors[k * 100 + j];
        red2[t] = acc;
    }
    __syncthreads();
    if (t < 100) spv[t] = red2[t] + red2[100 + t] + red2[200 + t] + red2[300 + t];
    __syncthreads();

    // b init
    for (int r = t; r < NPC * NJ; r += 1024) bst[r] = spv[r % 100] * 0.1f;

    // ---- pred phase: lane per (pair, o); 16 lanes/pair, 64 pairs/iter ----
    {
        const int g = t >> 4;                  // pair-slot 0..63
        const int o = t & 15;                  // output component
        const unsigned short* wp0 = dcWb + (size_t)g * 128 + o * 8;
#pragma unroll 2
        for (int iter = 0; iter < 50; ++iter) {
            const int p = iter * 64 + g;       // (n,j) pair 0..3199
            const int n = p / 100;
            const uint4 wq = *(const uint4*)(wp0 + (size_t)iter * 8192);
            const float4 pa = *(const float4*)&prim1[n * 8];
            const float4 pb = *(const float4*)&prim1[n * 8 + 4];
            float po = bf_lo(wq.x) * pa.x + bf_hi(wq.x) * pa.y
                     + bf_lo(wq.y) * pa.z + bf_hi(wq.y) * pa.w
                     + bf_lo(wq.z) * pb.x + bf_hi(wq.z) * pb.y
                     + bf_lo(wq.w) * pb.z + bf_hi(wq.w) * pb.w;
            const float po2 = __shfl_xor(po, 1);           // pred[o^1]
            if ((o & 1) == 0)
                predp[p * 9 + (o >> 1)] =
                    (unsigned)f2bfr(po) | ((unsigned)f2bfr(po2) << 16);
        }
    }
    __syncthreads();

    // ---- routing iterations ----
    for (int it = 0; it < 3; ++it) {
        // softmax stats per (n): 32 n x 32 lanes
        {
            const int n = t >> 5, q = t & 31;
            float mx = -1e30f;
            for (int j = q; j < 100; j += 32) mx = fmaxf(mx, bst[n * 100 + j]);
#pragma unroll
            for (int d = 1; d < 32; d <<= 1) mx = fmaxf(mx, __shfl_xor(mx, d));
            float se = 0.f;
            for (int j = q; j < 100; j += 32) se += __expf(bst[n * 100 + j] - mx);
#pragma unroll
            for (int d = 1; d < 32; d <<= 1) se += __shfl_xor(se, d);
            if (q == 0) { rmv[n] = mx; irsv[n] = 1.f / se; }
        }
        __syncthreads();
        for (int r = t; r < NPC * NJ; r += 1024)
            cst[r] = __expf(bst[r] - rmv[r / 100]) * irsv[r / 100];
        __syncthreads();

        // s-pass + squash: item = (j, op), 800 items, 1 per thread
        if (t < 800) {
            const int j = t >> 3, op = t & 7;
            float s0 = 0.f, s1 = 0.f;
#pragma unroll
            for (int n = 0; n < NPC; ++n) {
                const float c = cst[n * 100 + j];
                const unsigned pk = predp[(n * 100 + j) * 9 + op];
                s0 += c * bf_lo(pk);
                s1 += c * bf_hi(pk);
            }
            float sq = s0 * s0 + s1 * s1;
            sq += __shfl_xor(sq, 1);
            sq += __shfl_xor(sq, 2);
            sq += __shfl_xor(sq, 4);
            const float fv = (sq / (1.f + sq)) / sqrtf(sq + 1e-8f);
            svv[j * 18 + op * 2]     = fv * s0;
            svv[j * 18 + op * 2 + 1] = fv * s1;
        }
        __syncthreads();

        // a-pass: b += pred.v + sp*strength
        if (it < 2) {
            const float str = 0.1f - 0.02f * (float)(it + 1);
            for (int r = t; r < NPC * NJ; r += 1024) {
                const int j = r % 100;
                float a = 0.f;
#pragma unroll
                for (int op = 0; op < 8; ++op) {
                    const unsigned pk = predp[r * 9 + op];
                    const float2 vv = *(const float2*)&svv[j * 18 + op * 2];
                    a += bf_lo(pk) * vv.x + bf_hi(pk) * vv.y;
                }
                bst[r] += a + spv[j] * str;
            }
            __syncthreads();
        }
    }

    // ---- final: l2norm + logits ----
    if (t < 100) {
        const float T = *temp_p;
        float sq = 0.f, lg = 0.f;
#pragma unroll
        for (int o = 0; o < CD; ++o) {
            const float v = svv[t * 18 + o];
            sq += v * v;
            lg += v * targets[t * CD + o];
        }
        out[b * 100 + t] = lg * T / fmaxf(sqrtf(sq), 1e-12f);
    }
}

// ---------------------------------------------------------------------------
extern "C" void kernel_launch(void* const* d_in, const int* in_sizes, int n_in,
                              void* d_out, int out_size, void* d_ws, size_t ws_size,
                              hipStream_t stream)
{
    const float* features      = (const float*)d_in[0];
    const float* slot_features = (const float*)d_in[1];
    const float* W1            = (const float*)d_in[2];
    const float* b1            = (const float*)d_in[3];
    const float* W2            = (const float*)d_in[4];
    const float* b2            = (const float*)d_in[5];
    const float* ln_g          = (const float*)d_in[6];
    const float* ln_b          = (const float*)d_in[7];
    const float* pc_W          = (const float*)d_in[8];
    const float* pc_b          = (const float*)d_in[9];
    const float* pc_g          = (const float*)d_in[10];
    const float* pc_beta       = (const float*)d_in[11];
    const float* dc_W          = (const float*)d_in[12];
    const float* slot_priors   = (const float*)d_in[13];
    const float* targets       = (const float*)d_in[14];
    const float* temperature   = (const float*)d_in[15];
    float* out = (float*)d_out;

    unsigned short* Bt = (unsigned short*)d_ws;                    // 512*20000 bf16 = 20.48 MB
    float* h1 = (float*)((char*)d_ws + (size_t)512 * 20000 * 2);   // 4096*512
    float* h2 = h1 + (size_t)B_SZ * 512;                           // 4096*256
    float* h  = h2 + (size_t)B_SZ * 256;
    float* pr = h  + (size_t)B_SZ * 256;
    unsigned short* dcWb = (unsigned short*)(pr + (size_t)B_SZ * 256);  // 0.82 MB

    hipMemsetAsync(h1, 0, (size_t)B_SZ * 512 * sizeof(float), stream);

    transpose_cvt<<<dim3(625, 16), 256, 0, stream>>>(W1, Bt);
    cvt_dcw<<<200, 256, 0, stream>>>(dc_W, dcWb);
    gemm1_mfma<<<640, 256, 0, stream>>>(features, Bt, h1);
    gemm2_fused<<<dim3(256 / 64, B_SZ / 64), 256, 0, stream>>>(
        h1, b1, W2, b2, h2, B_SZ, 256, 512);
    layernorm256<<<B_SZ / 4, 256, 0, stream>>>(h2, ln_g, ln_b, h);
    prim_caps<<<B_SZ, 256, 0, stream>>>(h, pc_W, pc_b, pc_g, pc_beta, pr);
    routing_b1<<<B_SZ, 1024, 0, stream>>>(
        pr, slot_features, slot_priors, dcWb, targets, temperature, out);
}

// Round 3
// 1113.876 us; speedup vs baseline: 1.5243x; 1.0878x over previous
//
#include <hip/hip_runtime.h>
#include <hip/hip_bf16.h>

#define B_SZ   4096
#define NPC    32
#define NJ     100
#define CD     16
#define PD     8

typedef float  f32x4  __attribute__((ext_vector_type(4)));
typedef float  f32x2  __attribute__((ext_vector_type(2)));
typedef __bf16 bf16x8 __attribute__((ext_vector_type(8)));

__device__ __forceinline__ unsigned short f2bfr(float f) {
    union { float f; unsigned u; } v; v.f = f;
    return (unsigned short)((v.u + 0x8000u) >> 16);   // round-half-up to bf16
}
__device__ __forceinline__ float bf_lo(unsigned u) {
    union { unsigned u; float f; } v; v.u = u << 16; return v.f;
}
__device__ __forceinline__ float bf_hi(unsigned u) {
    union { unsigned u; float f; } v; v.u = u & 0xffff0000u; return v.f;
}

// ---------------------------------------------------------------------------
// W1 [20000][512] fp32  ->  Bt [512][20000] bf16 (transpose + convert)
// ---------------------------------------------------------------------------
__global__ __launch_bounds__(256) void transpose_cvt(
    const float* __restrict__ W, unsigned short* __restrict__ out)
{
    __shared__ float tile[32][33];
    const int kb = blockIdx.x * 32;     // 625 blocks
    const int nb = blockIdx.y * 32;     // 16 blocks
    const int tx = threadIdx.x & 31, ty = threadIdx.x >> 5;
#pragma unroll
    for (int i = 0; i < 4; ++i)
        tile[ty + 8 * i][tx] = W[(size_t)(kb + ty + 8 * i) * 512 + nb + tx];
    __syncthreads();
#pragma unroll
    for (int i = 0; i < 4; ++i)
        out[(size_t)(nb + ty + 8 * i) * 20000 + kb + tx] = f2bfr(tile[tx][ty + 8 * i]);
}

// ---------------------------------------------------------------------------
// dc_W [32*100*16*8] fp32 -> bf16, same element order
// ---------------------------------------------------------------------------
__global__ __launch_bounds__(256) void cvt_dcw(
    const float* __restrict__ W, unsigned short* __restrict__ out)
{
    const size_t i = ((size_t)blockIdx.x * 256 + threadIdx.x) * 8;  // 409600 total
    float4 f0 = *(const float4*)(W + i);
    float4 f1 = *(const float4*)(W + i + 4);
    uint4 o;
    o.x = (unsigned)f2bfr(f0.x) | ((unsigned)f2bfr(f0.y) << 16);
    o.y = (unsigned)f2bfr(f0.z) | ((unsigned)f2bfr(f0.w) << 16);
    o.z = (unsigned)f2bfr(f1.x) | ((unsigned)f2bfr(f1.y) << 16);
    o.w = (unsigned)f2bfr(f1.z) | ((unsigned)f2bfr(f1.w) << 16);
    *(uint4*)(out + i) = o;
}

// ---------------------------------------------------------------------------
// pc_W [32][256][8] -> pcWT [256][256] with pcWT[k][n*8+d] = pc_W[n][k][d]
// (makes the prim-caps dot coalesced across threads)
// ---------------------------------------------------------------------------
__global__ __launch_bounds__(256) void cvt_pcwt(
    const float* __restrict__ W, float* __restrict__ out)
{
    const int idx = blockIdx.x * 256 + threadIdx.x;   // 65536
    const int k = idx >> 8, c = idx & 255;
    const int n = c >> 3, d = c & 7;
    out[idx] = W[(size_t)(n * 256 + k) * 8 + d];
}

// ---------------------------------------------------------------------------
// GEMM1 (MFMA bf16): C += features @ W1.  128x128 tile, BK=32, split-K=5.
// XCD-bijective swizzle: g=(z,m) pinned to XCD g&7; the 4 n-blocks of one
// (z,m) sit at adjacent queue slots of the SAME XCD -> the 2 MB A-chunk is
// fetched once per XCD and hit 3x in L2 (A HBM: 1.31 GB -> ~0.33 GB).
// ---------------------------------------------------------------------------
__global__ __launch_bounds__(256) void gemm1_mfma(
    const float* __restrict__ A,            // [4096][20000] fp32
    const unsigned short* __restrict__ Bt,  // [512][20000] bf16
    float* __restrict__ C)                  // [4096][512] fp32 (zeroed)
{
    __shared__ __align__(16) unsigned short As[128 * 32];
    __shared__ __align__(16) unsigned short Bs[128 * 32];
    const int t = threadIdx.x;
    const int lane = t & 63, w = t >> 6;
    const int id = blockIdx.x;
    const int x  = id & 7;                  // XCD (heuristic: id % 8)
    const int q  = id >> 3;
    const int nb = q & 3;
    const int g  = (q >> 2) * 8 + x;        // 0..159 = (z, m)
    const int z  = g >> 5;                  // 0..4, K chunk of 4000
    const int m0 = (g & 31) * 128;
    const int n0 = nb * 128;

    const int srow = t >> 2, skc = t & 3;   // staging: slot t -> row, k-chunk
    const float*          Ap  = A  + (size_t)(m0 + srow) * 20000 + z * 4000 + skc * 8;
    const float*          Ap2 = Ap + (size_t)64 * 20000;
    const unsigned short* Bp  = Bt + (size_t)(n0 + srow) * 20000 + z * 4000 + skc * 8;
    const unsigned short* Bp2 = Bp + (size_t)64 * 20000;

    const int wr = w >> 1, wc = w & 1;      // wave -> 64x64 quadrant
    const int fr = lane & 15, fq = lane >> 4;

    f32x4 acc[4][4] = {};

    for (int kt = 0; kt < 125; ++kt) {
        const int k0 = kt * 32;
        float4 a0 = *(const float4*)(Ap  + k0);
        float4 a1 = *(const float4*)(Ap  + k0 + 4);
        float4 a2 = *(const float4*)(Ap2 + k0);
        float4 a3 = *(const float4*)(Ap2 + k0 + 4);
        uint4  q0 = *(const uint4*)(Bp  + k0);
        uint4  q1 = *(const uint4*)(Bp2 + k0);
        uint4 p0, p1;
        p0.x = (unsigned)f2bfr(a0.x) | ((unsigned)f2bfr(a0.y) << 16);
        p0.y = (unsigned)f2bfr(a0.z) | ((unsigned)f2bfr(a0.w) << 16);
        p0.z = (unsigned)f2bfr(a1.x) | ((unsigned)f2bfr(a1.y) << 16);
        p0.w = (unsigned)f2bfr(a1.z) | ((unsigned)f2bfr(a1.w) << 16);
        p1.x = (unsigned)f2bfr(a2.x) | ((unsigned)f2bfr(a2.y) << 16);
        p1.y = (unsigned)f2bfr(a2.z) | ((unsigned)f2bfr(a2.w) << 16);
        p1.z = (unsigned)f2bfr(a3.x) | ((unsigned)f2bfr(a3.y) << 16);
        p1.w = (unsigned)f2bfr(a3.z) | ((unsigned)f2bfr(a3.w) << 16);
        *(uint4*)(As + (size_t)t * 8)         = p0;
        *(uint4*)(As + (size_t)(t + 256) * 8) = p1;
        *(uint4*)(Bs + (size_t)t * 8)         = q0;
        *(uint4*)(Bs + (size_t)(t + 256) * 8) = q1;
        __syncthreads();
        bf16x8 af[4], bg[4];
#pragma unroll
        for (int mi = 0; mi < 4; ++mi)
            af[mi] = *(const bf16x8*)(As + (size_t)((wr * 64 + mi * 16 + fr) * 32 + fq * 8));
#pragma unroll
        for (int ni = 0; ni < 4; ++ni)
            bg[ni] = *(const bf16x8*)(Bs + (size_t)((wc * 64 + ni * 16 + fr) * 32 + fq * 8));
#pragma unroll
        for (int mi = 0; mi < 4; ++mi)
#pragma unroll
            for (int ni = 0; ni < 4; ++ni)
                acc[mi][ni] = __builtin_amdgcn_mfma_f32_16x16x32_bf16(
                    af[mi], bg[ni], acc[mi][ni], 0, 0, 0);
        __syncthreads();
    }

    // epilogue: C/D layout col=lane&15, row=(lane>>4)*4+reg
    const int er = fq * 4, ec = fr;
#pragma unroll
    for (int mi = 0; mi < 4; ++mi)
#pragma unroll
    for (int ni = 0; ni < 4; ++ni) {
        const size_t base = (size_t)(m0 + wr * 64 + mi * 16 + er) * 512
                          + n0 + wc * 64 + ni * 16 + ec;
#pragma unroll
        for (int r = 0; r < 4; ++r)
            atomicAdd(&C[base + (size_t)r * 512], acc[mi][ni][r]);
    }
}

// ---------------------------------------------------------------------------
// GEMM2: C = relu( relu(A + b1) @ B + b2 ), 32x64 tile -> 512 blocks (2/CU)
// ---------------------------------------------------------------------------
__global__ __launch_bounds__(256) void gemm2_fused(
    const float* __restrict__ A, const float* __restrict__ b1v,
    const float* __restrict__ Bm, const float* __restrict__ bias,
    float* __restrict__ C, int M, int N, int K)
{
    __shared__ float As[16][34];
    __shared__ float Bs[16][64];
    const int t  = threadIdx.x;
    const int tx = t & 15, ty = t >> 4;
    const int m0 = blockIdx.y * 32, n0 = blockIdx.x * 64;

    const int arow = t >> 3;            // 0..31
    const int ak   = (t & 7) << 1;      // 0..14 even
    const int bk   = t >> 4;
    const int bn   = (t & 15) << 2;

    const float* Aptr = A + (size_t)(m0 + arow) * K + ak;
    const float* Bptr = Bm + (size_t)bk * N + n0 + bn;

    float acc[2][4] = {};

    for (int k0 = 0; k0 < K; k0 += 16) {
        float2 av  = *(const float2*)(Aptr + k0);
        float2 b1q = *(const float2*)(b1v + k0 + ak);
        av.x = fmaxf(av.x + b1q.x, 0.f);
        av.y = fmaxf(av.y + b1q.y, 0.f);
        float4 bv = *(const float4*)(Bptr + (size_t)k0 * N);
        As[ak + 0][arow] = av.x;
        As[ak + 1][arow] = av.y;
        *(float4*)&Bs[bk][bn] = bv;
        __syncthreads();
#pragma unroll
        for (int kk = 0; kk < 16; ++kk) {
            float2 a = *(const float2*)&As[kk][ty << 1];
            float4 b = *(const float4*)&Bs[kk][tx << 2];
            acc[0][0] += a.x * b.x; acc[0][1] += a.x * b.y; acc[0][2] += a.x * b.z; acc[0][3] += a.x * b.w;
            acc[1][0] += a.y * b.x; acc[1][1] += a.y * b.y; acc[1][2] += a.y * b.z; acc[1][3] += a.y * b.w;
        }
        __syncthreads();
    }

    float4 bb = *(const float4*)(bias + n0 + (tx << 2));
#pragma unroll
    for (int i = 0; i < 2; ++i) {
        size_t m = (size_t)m0 + (ty << 1) + i;
        float4 o;
        o.x = fmaxf(acc[i][0] + bb.x, 0.f);
        o.y = fmaxf(acc[i][1] + bb.y, 0.f);
        o.z = fmaxf(acc[i][2] + bb.z, 0.f);
        o.w = fmaxf(acc[i][3] + bb.w, 0.f);
        *(float4*)(C + m * N + n0 + (tx << 2)) = o;
    }
}

// ---------------------------------------------------------------------------
// Fused LayerNorm(256) + primary caps.  One block per batch row.
// prim[b,n,d] = capsLN_d( LN(h2[b,:]) @ pcWT[:, n*8+d] + pc_b ) * g + beta
// pcWT reads are coalesced across threads (column-major access).
// ---------------------------------------------------------------------------
__global__ __launch_bounds__(256) void ln_prim(
    const float* __restrict__ h2, const float* __restrict__ lng,
    const float* __restrict__ lnb, const float* __restrict__ pcWT,
    const float* __restrict__ pcB, const float* __restrict__ pcG,
    const float* __restrict__ pcBeta, float* __restrict__ prim)
{
    __shared__ float hs[256];
    __shared__ float tmp[256];
    __shared__ float r8[8];
    const int t = threadIdx.x;
    const int lane = t & 63, w = t >> 6;
    const size_t b = blockIdx.x;

    float x = h2[b * 256 + t];
    float s = x, s2 = x * x;
#pragma unroll
    for (int off = 32; off; off >>= 1) {
        s  += __shfl_xor(s, off);
        s2 += __shfl_xor(s2, off);
    }
    if (lane == 0) { r8[w] = s; r8[4 + w] = s2; }
    __syncthreads();
    s  = r8[0] + r8[1] + r8[2] + r8[3];
    s2 = r8[4] + r8[5] + r8[6] + r8[7];
    float mu   = s * (1.f / 256.f);
    float var  = s2 * (1.f / 256.f) - mu * mu;
    float rstd = rsqrtf(var + 1e-5f);
    hs[t] = (x - mu) * rstd * lng[t] + lnb[t];
    __syncthreads();

    float acc = pcB[t];
#pragma unroll 4
    for (int k = 0; k < 256; ++k) acc += hs[k] * pcWT[k * 256 + t];
    tmp[t] = acc;
    __syncthreads();

    const int n = t >> 3;
    float cmu = 0.f, cs2 = 0.f;
    const int base = n << 3;
#pragma unroll
    for (int qq = 0; qq < 8; ++qq) {
        float xx = tmp[base + qq];
        cmu += xx;
        cs2 += xx * xx;
    }
    cmu *= 0.125f;
    cs2 = cs2 * 0.125f - cmu * cmu;
    float crstd = rsqrtf(cs2 + 1e-5f);
    prim[b * 256 + t] = (acc - cmu) * crstd * pcG[t] + pcBeta[t];
}

// ---------------------------------------------------------------------------
// Routing, 1 batch row per block, 1024 threads (16 waves -> 4 waves/SIMD).
// pred phase: thread owns an o-PAIR (8 lanes per (n,j) pair) -> no shuffles,
// no predication, 25 iters.  s/a-pass accumulate in f32x2 (v_pk_fma_f32).
// ---------------------------------------------------------------------------
__global__ __launch_bounds__(1024, 4) void routing_b1(
    const float* __restrict__ prim,            // [B,32,8]
    const float* __restrict__ sf,              // [B,100]
    const float* __restrict__ priors,          // [100,100]
    const unsigned short* __restrict__ dcWb,   // [32,100,16,8] bf16
    const float* __restrict__ targets,         // [100,16]
    const float* __restrict__ temp_p,
    float* __restrict__ out)                   // [B,100]
{
    __shared__ __align__(16) float prim1[256];
    __shared__ unsigned predp[NPC * NJ * 9];   // [n*100+j][op0..7], stride 9: 115200 B
    __shared__ float    bst[NPC * NJ];         // fp32 b-state
    __shared__ float    cst[NPC * NJ];         // softmax coupling c
    __shared__ __align__(16) float svv[NJ * 18]; // v vectors, stride 18
    __shared__ float    spv[NJ];
    __shared__ float    rmv[NPC], irsv[NPC];
    __shared__ float    red[512];
    __shared__ float    red2[400];
    __shared__ float    ssum;

    const int t = threadIdx.x;                 // 0..1023
    const int lane = t & 63, w = t >> 6;       // w 0..15

    const size_t b = blockIdx.x;

    if (t < 256) prim1[t] = prim[b * 256 + t];
    if (t < 128) red[t] = (t < 100) ? fmaxf(sf[b * 100 + t], 0.f) : 0.f;
    __syncthreads();

    // sum of relu (2 waves reduce)
    if (t < 128) {
        float v = red[t];
#pragma unroll
        for (int d = 32; d; d >>= 1) v += __shfl_xor(v, d);
        if (lane == 0) red[128 + w] = v;
    }
    __syncthreads();
    if (t == 0) ssum = fmaxf(red[128] + red[129], 1e-6f);
    __syncthreads();

    // sp[j] = sum_k (relu_k/ssum - 0.01) * priors[k][j]   (4-way k-split)
    if (t < 400) {
        const int j = t % 100, q = t / 100;
        const float inv = 1.f / ssum;
        float acc = 0.f;
#pragma unroll 5
        for (int k = q * 25; k < q * 25 + 25; ++k)
            acc += (red[k] * inv - 0.01f) * priors[k * 100 + j];
        red2[t] = acc;
    }
    __syncthreads();
    if (t < 100) spv[t] = red2[t] + red2[100 + t] + red2[200 + t] + red2[300 + t];
    __syncthreads();

    // b init
    for (int r = t; r < NPC * NJ; r += 1024) bst[r] = spv[r % 100] * 0.1f;

    // ---- pred phase: thread = (pair-slot g8, op); 128 pairs/iter, 25 iters.
    // Each thread computes pred[p][2op] and pred[p][2op+1] (16 MACs) and
    // packs them into predp[p*9+op].  Loads: 8 lanes x 32B = 256B/pair.
    {
        const int g8 = t >> 3;                 // pair-slot 0..127
        const int op = t & 7;                  // o-pair index
        const unsigned short* wp0 = dcWb + (size_t)g8 * 128 + op * 16;
#pragma unroll 5
        for (int iter = 0; iter < 25; ++iter) {
            const int p = iter * 128 + g8;     // (n,j) pair 0..3199
            const int n = p / 100;
            const uint4 w0 = *(const uint4*)(wp0 + (size_t)iter * 16384);
            const uint4 w1 = *(const uint4*)(wp0 + (size_t)iter * 16384 + 8);
            const float4 pa = *(const float4*)&prim1[n * 8];
            const float4 pb = *(const float4*)&prim1[n * 8 + 4];
            float po  = bf_lo(w0.x) * pa.x + bf_hi(w0.x) * pa.y
                      + bf_lo(w0.y) * pa.z + bf_hi(w0.y) * pa.w
                      + bf_lo(w0.z) * pb.x + bf_hi(w0.z) * pb.y
                      + bf_lo(w0.w) * pb.z + bf_hi(w0.w) * pb.w;
            float po2 = bf_lo(w1.x) * pa.x + bf_hi(w1.x) * pa.y
                      + bf_lo(w1.y) * pa.z + bf_hi(w1.y) * pa.w
                      + bf_lo(w1.z) * pb.x + bf_hi(w1.z) * pb.y
                      + bf_lo(w1.w) * pb.z + bf_hi(w1.w) * pb.w;
            predp[p * 9 + op] =
                (unsigned)f2bfr(po) | ((unsigned)f2bfr(po2) << 16);
        }
    }
    __syncthreads();

    // ---- routing iterations ----
    for (int it = 0; it < 3; ++it) {
        // softmax stats per (n): 32 n x 32 lanes
        {
            const int n = t >> 5, q = t & 31;
            float mx = -1e30f;
            for (int j = q; j < 100; j += 32) mx = fmaxf(mx, bst[n * 100 + j]);
#pragma unroll
            for (int d = 1; d < 32; d <<= 1) mx = fmaxf(mx, __shfl_xor(mx, d));
            float se = 0.f;
            for (int j = q; j < 100; j += 32) se += __expf(bst[n * 100 + j] - mx);
#pragma unroll
            for (int d = 1; d < 32; d <<= 1) se += __shfl_xor(se, d);
            if (q == 0) { rmv[n] = mx; irsv[n] = 1.f / se; }
        }
        __syncthreads();
        for (int r = t; r < NPC * NJ; r += 1024)
            cst[r] = __expf(bst[r] - rmv[r / 100]) * irsv[r / 100];
        __syncthreads();

        // s-pass + squash: item = (j, op), 800 items, 1 per thread
        if (t < 800) {
            const int j = t >> 3, op = t & 7;
            f32x2 acc2 = {0.f, 0.f};
#pragma unroll
            for (int n = 0; n < NPC; ++n) {
                const float c = cst[n * 100 + j];
                const unsigned pk = predp[(n * 100 + j) * 9 + op];
                f32x2 pv = {bf_lo(pk), bf_hi(pk)};
                f32x2 c2 = {c, c};
                acc2 += pv * c2;
            }
            float s0 = acc2.x, s1 = acc2.y;
            float sq = s0 * s0 + s1 * s1;
            sq += __shfl_xor(sq, 1);
            sq += __shfl_xor(sq, 2);
            sq += __shfl_xor(sq, 4);
            const float fv = (sq / (1.f + sq)) / sqrtf(sq + 1e-8f);
            svv[j * 18 + op * 2]     = fv * s0;
            svv[j * 18 + op * 2 + 1] = fv * s1;
        }
        __syncthreads();

        // a-pass: b += pred.v + sp*strength
        if (it < 2) {
            const float str = 0.1f - 0.02f * (float)(it + 1);
            for (int r = t; r < NPC * NJ; r += 1024) {
                const int j = r % 100;
                f32x2 a2 = {0.f, 0.f};
#pragma unroll
                for (int op = 0; op < 8; ++op) {
                    const unsigned pk = predp[r * 9 + op];
                    const f32x2 vv = *(const f32x2*)&svv[j * 18 + op * 2];
                    f32x2 pv = {bf_lo(pk), bf_hi(pk)};
                    a2 += pv * vv;
                }
                bst[r] += (a2.x + a2.y) + spv[j] * str;
            }
            __syncthreads();
        }
    }

    // ---- final: l2norm + logits ----
    if (t < 100) {
        const float T = *temp_p;
        float sq = 0.f, lg = 0.f;
#pragma unroll
        for (int o = 0; o < CD; ++o) {
            const float v = svv[t * 18 + o];
            sq += v * v;
            lg += v * targets[t * CD + o];
        }
        out[b * 100 + t] = lg * T / fmaxf(sqrtf(sq), 1e-12f);
    }
}

// ---------------------------------------------------------------------------
extern "C" void kernel_launch(void* const* d_in, const int* in_sizes, int n_in,
                              void* d_out, int out_size, void* d_ws, size_t ws_size,
                              hipStream_t stream)
{
    const float* features      = (const float*)d_in[0];
    const float* slot_features = (const float*)d_in[1];
    const float* W1            = (const float*)d_in[2];
    const float* b1            = (const float*)d_in[3];
    const float* W2            = (const float*)d_in[4];
    const float* b2            = (const float*)d_in[5];
    const float* ln_g          = (const float*)d_in[6];
    const float* ln_b          = (const float*)d_in[7];
    const float* pc_W          = (const float*)d_in[8];
    const float* pc_b          = (const float*)d_in[9];
    const float* pc_g          = (const float*)d_in[10];
    const float* pc_beta       = (const float*)d_in[11];
    const float* dc_W          = (const float*)d_in[12];
    const float* slot_priors   = (const float*)d_in[13];
    const float* targets       = (const float*)d_in[14];
    const float* temperature   = (const float*)d_in[15];
    float* out = (float*)d_out;

    unsigned short* Bt = (unsigned short*)d_ws;                    // 512*20000 bf16 = 20.48 MB
    float* h1 = (float*)((char*)d_ws + (size_t)512 * 20000 * 2);   // 4096*512
    float* h2 = h1 + (size_t)B_SZ * 512;                           // 4096*256
    float* pcWT = h2 + (size_t)B_SZ * 256;                         // 256*256 (reuses old h slot)
    float* pr = pcWT + (size_t)B_SZ * 256;
    unsigned short* dcWb = (unsigned short*)(pr + (size_t)B_SZ * 256);  // 0.82 MB

    hipMemsetAsync(h1, 0, (size_t)B_SZ * 512 * sizeof(float), stream);

    transpose_cvt<<<dim3(625, 16), 256, 0, stream>>>(W1, Bt);
    cvt_dcw<<<200, 256, 0, stream>>>(dc_W, dcWb);
    cvt_pcwt<<<256, 256, 0, stream>>>(pc_W, pcWT);
    gemm1_mfma<<<640, 256, 0, stream>>>(features, Bt, h1);
    gemm2_fused<<<dim3(256 / 64, B_SZ / 32), 256, 0, stream>>>(
        h1, b1, W2, b2, h2, B_SZ, 256, 512);
    ln_prim<<<B_SZ, 256, 0, stream>>>(h2, ln_g, ln_b, pcWT, pc_b, pc_g, pc_beta, pr);
    routing_b1<<<B_SZ, 1024, 0, stream>>>(
        pr, slot_features, slot_priors, dcWb, targets, temperature, out);
}